// Round 12
// baseline (194.184 us; speedup 1.0000x reference)
//
#include <hip/hip_runtime.h>
#include <hip/hip_bf16.h>

typedef __attribute__((ext_vector_type(4))) float f32x4;
typedef __attribute__((ext_vector_type(8))) short s16x8;
typedef unsigned int uint;
typedef unsigned short ushort;
typedef unsigned long long u64;

// N=8192, INP=512, OUT=256
// out = relu(D^-1/2 (binA+I) D^-1/2 (x@w)) @ lin_w^T + lin_b
// R12: k_pack (2048 blocks) + ONE fused kernel (grid 256 = #CUs, co-resident,
// 2 device spin-barriers) running xw -> spmm -> lin. Phase bodies = R11 verbatim.
// PB tiled: byte((n,k)) = (k>>5)*16384+(n>>4)*1024+((k>>3)&3)*256+(n&15)*16+(k&7)*2
// part2[mt 256][kc 4][n 256][m&31 32] bf16

__device__ inline ushort f2bf(float f) {
  union { float f; uint u; } v; v.f = f;
  uint r = (v.u + 0x7FFFu + ((v.u >> 16) & 1u)) >> 16;   // RNE
  return (ushort)r;
}
__device__ inline float bf2f(ushort h) { union { uint u; float f; } v; v.u = ((uint)h) << 16; return v.f; }
__device__ inline uint pack2(float a, float b) { return (uint)f2bf(a) | ((uint)f2bf(b) << 16); }
__device__ inline int kappa(int j) {
  return (j & ~255) | ((j & 3) << 6) | (((j >> 7) & 1) << 5) | ((j >> 2) & 31);
}
__device__ inline int ikappa(int k) {
  return (k & ~255) | ((k >> 6) & 3) | (((k >> 5) & 1) << 7) | ((k & 31) << 2);
}

__device__ inline void gridbar(uint* ctr, int phase) {
  __syncthreads();
  if (threadIdx.x == 0) {
    __threadfence();
    __hip_atomic_fetch_add(&ctr[phase], 1u, __ATOMIC_ACQ_REL, __HIP_MEMORY_SCOPE_AGENT);
    while (__hip_atomic_load(&ctr[phase], __ATOMIC_ACQUIRE, __HIP_MEMORY_SCOPE_AGENT) < 256u)
      __builtin_amdgcn_s_sleep(2);
    __threadfence();
  }
  __syncthreads();
}

// ---------------- K1: ballot bit-pack, 1 row/wave, depth-2 pipeline ----------
__global__ __launch_bounds__(256, 4) void k_pack(const float* __restrict__ adj,
                                                 const float* __restrict__ w,
                                                 const float* __restrict__ lw,
                                                 uint* __restrict__ bits,
                                                 float* __restrict__ dinv,
                                                 float* __restrict__ dk,
                                                 ushort* __restrict__ wT,
                                                 ushort* __restrict__ lwb) {
  const int t = threadIdx.x, lane = t & 63, wv = t >> 6;
  const int b = blockIdx.x;
  const int row = b * 4 + wv;
  const float4* src = (const float4*)(adj + (size_t)row * 8192) + lane;
  uint* dst = bits + (size_t)row * 256;
  float4 A[4], B[4], C[4];
#pragma unroll
  for (int j = 0; j < 4; ++j) A[j] = src[j * 64];
#pragma unroll
  for (int j = 0; j < 4; ++j) B[j] = src[256 + j * 64];
  int cnt = 0;
#pragma unroll
  for (int bt = 0; bt < 8; ++bt) {
    if (bt + 2 < 8) {
#pragma unroll
      for (int j = 0; j < 4; ++j) C[j] = src[(bt + 2) * 256 + j * 64];
    }
#pragma unroll
    for (int j = 0; j < 4; ++j) {
      u64 b0 = __ballot(A[j].x > 0.5f), b1 = __ballot(A[j].y > 0.5f);
      u64 b2 = __ballot(A[j].z > 0.5f), b3 = __ballot(A[j].w > 0.5f);
      cnt += __popcll(b0) + __popcll(b1) + __popcll(b2) + __popcll(b3);
      if ((lane & 31) == 0) {
        uint4 v = (lane == 0)
          ? make_uint4((uint)b0, (uint)(b0 >> 32), (uint)b1, (uint)(b1 >> 32))
          : make_uint4((uint)b2, (uint)(b2 >> 32), (uint)b3, (uint)(b3 >> 32));
        *(uint4*)(dst + (bt * 4 + j) * 8 + (lane >> 5) * 4) = v;
      }
    }
#pragma unroll
    for (int j = 0; j < 4; ++j) { A[j] = B[j]; B[j] = C[j]; }
  }
  if (lane == 0) {
    float d = rsqrtf((float)(cnt + 1));
    dinv[row] = d;
    dk[kappa(row)] = d;
  }
  if (b < 16) {
#pragma unroll
    for (int kk = 0; kk < 32; ++kk) {
      int k = b * 32 + kk;
      wT[(size_t)t * 512 + k] = f2bf(w[(size_t)k * 256 + t]);
    }
  } else if (b < 24) {
    const int b2 = b - 16;
    const float4* s = (const float4*)lw + b2 * 2048;
    uint2* d = (uint2*)lwb + b2 * 2048;
#pragma unroll
    for (int ii = 0; ii < 8; ++ii) {
      float4 v = s[ii * 256 + t];
      uint2 p; p.x = pack2(v.x, v.y); p.y = pack2(v.z, v.w);
      d[ii * 256 + t] = p;
    }
  }
}

// ---------------- K2 fused: xw -> [bar] -> spmm -> [bar] -> lin --------------
__global__ __launch_bounds__(512, 1) void k_mega(
    const float* __restrict__ x, const ushort* __restrict__ wT,
    const float* __restrict__ dk, const float* __restrict__ dinv,
    const uint* __restrict__ bits, const ushort* __restrict__ lwb,
    const float* __restrict__ lb,
    ushort* __restrict__ PB, ushort* __restrict__ zRow,
    ushort* __restrict__ part2, float* __restrict__ out, uint* ctr) {
  __shared__ __align__(16) char smem[33024];
  __shared__ uint2 lut[16];
  __shared__ float sdinv[32];
  const int b = blockIdx.x;
  const int t = threadIdx.x;
  const int lane = t & 63, wid = t >> 6;
  const int rl = lane & 15, kg = lane >> 4;

  // ===== phase X: PB + zRow = dk[k]*(x@w) (R11 k_xw body) =====
  {
    ushort* xa0 = (ushort*)smem;              // 4 KB
    ushort* xa1 = (ushort*)(smem + 4096);     // 4 KB
    ushort* zs  = (ushort*)(smem + 8192);     // 16.5 KB (32*264)
    const int bp = (b & 3) * 64 + (b >> 2);
    const int mg = wid >> 2, ng = wid & 3;
    const int srow = t >> 4, sseg = t & 15;
    const int jrow = ((bp >> 3) << 8) + ((bp & 1) << 7) + ((bp >> 1) & 3) + srow * 4;
    const float4* xsrc = (const float4*)(x + (size_t)jrow * 512) + sseg;
    const int swb = (sseg * 8) ^ ((srow & 7) << 4);
    const int arow = mg * 16 + rl;
    float4 xv[8];
#pragma unroll
    for (int kc2 = 0; kc2 < 8; kc2++) xv[kc2] = xsrc[kc2 * 16];

    f32x4 acc[4];
#pragma unroll
    for (int q = 0; q < 4; q++) acc[q] = (f32x4){0.f, 0.f, 0.f, 0.f};

    {
      uint2 pk; pk.x = pack2(xv[0].x, xv[0].y); pk.y = pack2(xv[0].z, xv[0].w);
      *(uint2*)((char*)xa0 + srow * 128 + swb) = pk;
    }
#pragma unroll
    for (int kc2 = 0; kc2 < 8; kc2++) {
      __syncthreads();
      if (kc2 < 7) {
        ushort* xan = (kc2 & 1) ? xa0 : xa1;
        uint2 pk; pk.x = pack2(xv[kc2 + 1].x, xv[kc2 + 1].y);
        pk.y = pack2(xv[kc2 + 1].z, xv[kc2 + 1].w);
        *(uint2*)((char*)xan + srow * 128 + swb) = pk;
      }
      ushort* xac = (kc2 & 1) ? xa1 : xa0;
#pragma unroll
      for (int ks = 0; ks < 2; ks++) {
        union { uint4 u; s16x8 s; } av;
        av.u = *(uint4*)((char*)xac + arow * 128 + ((ks * 64 + kg * 16) ^ ((rl & 7) << 4)));
#pragma unroll
        for (int q = 0; q < 4; q++) {
          int n = ng * 64 + q * 16 + rl;
          union { uint4 u; s16x8 s; } bv;
          bv.u = *(const uint4*)(wT + (size_t)n * 512 + kc2 * 64 + ks * 32 + kg * 8);
          acc[q] = __builtin_amdgcn_mfma_f32_16x16x32_bf16(av.s, bv.s, acc[q], 0, 0, 0);
        }
      }
    }
    const int kb = bp * 32 + mg * 16 + kg * 4;
    float4 dk4 = *(const float4*)(dk + kb);
    const float dkv[4] = {dk4.x, dk4.y, dk4.z, dk4.w};
    char* pb0 = (char*)PB + (size_t)bp * 16384 + (mg * 2 + (kg >> 1)) * 256 + rl * 16 + (kg & 1) * 8;
    const int kk0 = mg * 16 + kg * 4;
#pragma unroll
    for (int q = 0; q < 4; q++) {
      int n = ng * 64 + q * 16 + rl;
      ushort zu[4];
#pragma unroll
      for (int r = 0; r < 4; r++) zu[r] = f2bf(acc[q][r] * dkv[r]);
      uint2 p;
      p.x = (uint)zu[0] | ((uint)zu[1] << 16);
      p.y = (uint)zu[2] | ((uint)zu[3] << 16);
      *(uint2*)(pb0 + (ng * 4 + q) * 1024) = p;
#pragma unroll
      for (int r = 0; r < 4; r++) zs[(kk0 + r) * 264 + n] = zu[r];
    }
    __syncthreads();
    {
      const int rr = t >> 4, seg = t & 15;
      uint4 v0 = *(uint4*)&zs[rr * 264 + seg * 16];
      uint4 v1 = *(uint4*)&zs[rr * 264 + seg * 16 + 8];
      ushort* dstz = zRow + (size_t)ikappa(bp * 32 + rr) * 256 + seg * 16;
      *(uint4*)dstz = v0;
      *(uint4*)(dstz + 8) = v1;
    }
  }
  gridbar(ctr, 0);

  // ===== phase S: part2 = (binA[:,kc] @ z[kc])^T (R11 k_spmm body) =====
  {
    uint4* blds4 = (uint4*)smem;   // 32 KB
    const int kc = b & 3, mb = b >> 2;
    const int m0 = mb * 128;
    const int mg = wid >> 2, ng = wid & 3;
    if (t < 16) {
      uint2 e;
      e.x = ((t & 1u) ? 0x3F80u : 0u) | ((t & 2u) ? 0x3F800000u : 0u);
      e.y = ((t & 4u) ? 0x3F80u : 0u) | ((t & 8u) ? 0x3F800000u : 0u);
      lut[t] = e;
    }
    {
      const int r = t >> 2, p = t & 3;
      const uint4* src = (const uint4*)(bits + (size_t)(m0 + r) * 256 + kc * 64);
#pragma unroll
      for (int i = 0; i < 4; ++i) {
        int g = p * 4 + i;
        blds4[r * 16 + (g ^ (r & 15))] = src[g];
      }
    }
    const char* zb0 = (const char*)PB + (size_t)kc * 64 * 16384 + ng * 4096 + kg * 256 + rl * 16;
    __syncthreads();

    uint4 bufA[4], bufB[4];
#pragma unroll
    for (int q = 0; q < 4; ++q) bufA[q] = *(const uint4*)(zb0 + q * 1024);

    f32x4 acc[4][4];
#pragma unroll
    for (int f = 0; f < 4; ++f)
#pragma unroll
      for (int q = 0; q < 4; ++q) acc[f][q] = (f32x4){0.f, 0.f, 0.f, 0.f};

    int abase[4];
#pragma unroll
    for (int f = 0; f < 4; ++f) abase[f] = (mg * 64 + f * 16 + rl) * 16;
    const int axor = rl;
    const uint shft = kg * 8;

    for (int a = 0; a < 16; ++a) {
      uint4 aw[4];
#pragma unroll
      for (int f = 0; f < 4; ++f) aw[f] = blds4[abase[f] + (a ^ axor)];
#pragma unroll
      for (int s = 0; s < 4; ++s) {
        const int ks = a * 4 + s;
        const uint4* use = (s & 1) ? bufB : bufA;
        uint4* nxt = (s & 1) ? bufA : bufB;
        if (ks < 63) {
#pragma unroll
          for (int q = 0; q < 4; ++q)
            nxt[q] = *(const uint4*)(zb0 + (size_t)(ks + 1) * 16384 + q * 1024);
        }
#pragma unroll
        for (int f = 0; f < 4; ++f) {
          uint wrd = (s == 0) ? aw[f].x : (s == 1) ? aw[f].y : (s == 2) ? aw[f].z : aw[f].w;
          uint byt = (wrd >> shft) & 0xFFu;
          uint2 lo = lut[byt & 0xFu];
          uint2 hi = lut[byt >> 4];
          union { uint4 u; s16x8 s8; } au;
          au.u = make_uint4(lo.x, lo.y, hi.x, hi.y);
#pragma unroll
          for (int q = 0; q < 4; ++q) {
            union { uint4 u; s16x8 s8; } bu; bu.u = use[q];
            acc[f][q] = __builtin_amdgcn_mfma_f32_16x16x32_bf16(au.s8, bu.s8, acc[f][q], 0, 0, 0);
          }
        }
      }
    }
#pragma unroll
    for (int f = 0; f < 4; ++f)
#pragma unroll
      for (int q = 0; q < 4; ++q) {
        int n = ng * 64 + q * 16 + rl;
        int mt = mb * 4 + mg * 2 + (f >> 1);
        int moff = (f & 1) * 16 + kg * 4;
        uint2 p;
        p.x = pack2(acc[f][q][0], acc[f][q][1]);
        p.y = pack2(acc[f][q][2], acc[f][q][3]);
        *(uint2*)(part2 + ((((size_t)mt * 4 + kc) * 256 + n) * 32 + moff)) = p;
      }
  }
  gridbar(ctr, 1);

  // ===== phase L: h = relu(d_m*(sum part2 + zRow)); out = h @ lwb^T + lb =====
  {
    ushort* hA = (ushort*)smem;   // 16 KB
    const int m0 = b * 32;
    if (t < 32) sdinv[t] = dinv[m0 + t];
    {
      const int n = t & 255, mh = t >> 8;
      float sum[16];
#pragma unroll
      for (int j = 0; j < 16; ++j)
        sum[j] = bf2f(zRow[(size_t)(m0 + mh * 16 + j) * 256 + n]);
#pragma unroll
      for (int kcp = 0; kcp < 4; kcp++) {
        const ushort* pp = part2 + (((size_t)b * 4 + kcp) * 256 + n) * 32 + mh * 16;
        uint4 pa = *(const uint4*)pp, pbq = *(const uint4*)(pp + 8);
        uint pu[8] = {pa.x, pa.y, pa.z, pa.w, pbq.x, pbq.y, pbq.z, pbq.w};
#pragma unroll
        for (int i = 0; i < 8; i++) {
          sum[2 * i]     += bf2f((ushort)(pu[i] & 0xFFFF));
          sum[2 * i + 1] += bf2f((ushort)(pu[i] >> 16));
        }
      }
      __syncthreads();
#pragma unroll
      for (int j = 0; j < 16; j++) {
        int m = mh * 16 + j;
        float h = sum[j] * sdinv[m];
        h = h > 0.f ? h : 0.f;
        *(ushort*)((char*)hA + m * 512 + ((n * 2) ^ ((m & 7) << 4))) = f2bf(h);
      }
    }
    __syncthreads();
    f32x4 acc[2][2];
#pragma unroll
    for (int f = 0; f < 2; f++)
#pragma unroll
      for (int q = 0; q < 2; q++) acc[f][q] = (f32x4){0.f, 0.f, 0.f, 0.f};

#pragma unroll
    for (int ks = 0; ks < 8; ks++) {
      union { uint4 u; s16x8 s; } av[2];
#pragma unroll
      for (int f = 0; f < 2; f++)
        av[f].u = *(uint4*)((char*)hA + (f * 16 + rl) * 512 + ((ks * 64 + kg * 16) ^ ((rl & 7) << 4)));
#pragma unroll
      for (int q = 0; q < 2; q++) {
        int no = wid * 32 + q * 16 + rl;
        union { uint4 u; s16x8 s; } bv;
        bv.u = *(const uint4*)(lwb + (size_t)no * 256 + ks * 32 + kg * 8);
#pragma unroll
        for (int f = 0; f < 2; f++)
          acc[f][q] = __builtin_amdgcn_mfma_f32_16x16x32_bf16(av[f].s, bv.s, acc[f][q], 0, 0, 0);
      }
    }
#pragma unroll
    for (int q = 0; q < 2; q++) {
      int no = wid * 32 + q * 16 + rl;
      float bb = lb[no];
#pragma unroll
      for (int f = 0; f < 2; f++) {
        int mbase = m0 + f * 16 + kg * 4;
#pragma unroll
        for (int r = 0; r < 4; r++)
          out[(size_t)(mbase + r) * 256 + no] = acc[f][q][r] + bb;
      }
    }
  }
}

extern "C" void kernel_launch(void* const* d_in, const int* in_sizes, int n_in,
                              void* d_out, int out_size, void* d_ws, size_t ws_size,
                              hipStream_t stream) {
  const float* x   = (const float*)d_in[0];
  const float* adj = (const float*)d_in[1];
  const float* w   = (const float*)d_in[2];
  const float* lw  = (const float*)d_in[3];
  const float* lb  = (const float*)d_in[4];
  float* out = (float*)d_out;

  char* ws = (char*)d_ws;
  float*  dinv  = (float*)(ws + 0);                 // 32 KB
  float*  dk    = (float*)(ws + (32u << 10));       // 32 KB (permuted)
  uint*   ctr   = (uint*)(ws + (96u << 10));        // 16 B barrier counters
  ushort* lwb   = (ushort*)(ws + (128u << 10));     // 128 KB
  ushort* wT    = (ushort*)(ws + (256u << 10));     // 256 KB
  uint*   bits  = (uint*)(ws + (1ull << 20));       // 8 MB
  ushort* PB    = (ushort*)(ws + (9ull << 20));     // 4 MB (tiled z)
  ushort* part2 = (ushort*)(ws + (16ull << 20));    // 16 MB [mt][kc][n][m&31]
  ushort* zRow  = (ushort*)(ws + (48ull << 20));    // 4 MB  [m][n]

  hipMemsetAsync(ctr, 0, 16, stream);
  hipLaunchKernelGGL(k_pack, dim3(2048), dim3(256), 0, stream, adj, w, lw, bits, dinv, dk, wT, lwb);
  hipLaunchKernelGGL(k_mega, dim3(256), dim3(512), 0, stream,
                     x, wT, dk, dinv, bits, lwb, lb, PB, zRow, part2, out, ctr);
}

// Round 13
// 120.395 us; speedup vs baseline: 1.6129x; 1.6129x over previous
//
#include <hip/hip_runtime.h>
#include <hip/hip_bf16.h>

typedef __attribute__((ext_vector_type(4))) float f32x4;
typedef __attribute__((ext_vector_type(8))) short s16x8;
typedef unsigned int uint;
typedef unsigned short ushort;
typedef unsigned long long u64;

// N=8192, INP=512, OUT=256
// out = relu(D^-1/2 (binA+I) D^-1/2 (x@w)) @ lin_w^T + lin_b
// binA packed via wave ballot (k permuted by kappa); bf16 MFMA GEMMs.
// PB tiled: byte((n,k)) = (k>>5)*16384+(n>>4)*1024+((k>>3)&3)*256+(n&15)*16+(k&7)*2
// part2[mt 256][kc 4][n 256][m&31 32] bf16
// R13: revert R12 fusion (per-block device fences cost ~74us). R11 structure +
//      wT/lwb prep distributed over 288 k_pack blocks (kills straggler tail).

__device__ inline ushort f2bf(float f) {
  union { float f; uint u; } v; v.f = f;
  uint r = (v.u + 0x7FFFu + ((v.u >> 16) & 1u)) >> 16;   // RNE
  return (ushort)r;
}
__device__ inline float bf2f(ushort h) { union { uint u; float f; } v; v.u = ((uint)h) << 16; return v.f; }
__device__ inline uint pack2(float a, float b) { return (uint)f2bf(a) | ((uint)f2bf(b) << 16); }
__device__ inline int kappa(int j) {
  return (j & ~255) | ((j & 3) << 6) | (((j >> 7) & 1) << 5) | ((j >> 2) & 31);
}
__device__ inline int ikappa(int k) {
  return (k & ~255) | ((k >> 6) & 3) | (((k >> 5) & 1) << 7) | ((k & 31) << 2);
}

// ---------------- K1: ballot bit-pack, 1 row/wave, depth-2 pipeline ----------
__global__ __launch_bounds__(256, 4) void k_pack(const float* __restrict__ adj,
                                                 const float* __restrict__ w,
                                                 const float* __restrict__ lw,
                                                 uint* __restrict__ bits,
                                                 float* __restrict__ dinv,
                                                 float* __restrict__ dk,
                                                 ushort* __restrict__ wT,
                                                 ushort* __restrict__ lwb) {
  const int t = threadIdx.x, lane = t & 63, wv = t >> 6;
  const int b = blockIdx.x;
  const int row = b * 4 + wv;
  const float4* src = (const float4*)(adj + (size_t)row * 8192) + lane;
  uint* dst = bits + (size_t)row * 256;
  float4 A[4], B[4], C[4];
#pragma unroll
  for (int j = 0; j < 4; ++j) A[j] = src[j * 64];
#pragma unroll
  for (int j = 0; j < 4; ++j) B[j] = src[256 + j * 64];
  int cnt = 0;
#pragma unroll
  for (int bt = 0; bt < 8; ++bt) {
    if (bt + 2 < 8) {
#pragma unroll
      for (int j = 0; j < 4; ++j) C[j] = src[(bt + 2) * 256 + j * 64];
    }
#pragma unroll
    for (int j = 0; j < 4; ++j) {
      u64 b0 = __ballot(A[j].x > 0.5f), b1 = __ballot(A[j].y > 0.5f);
      u64 b2 = __ballot(A[j].z > 0.5f), b3 = __ballot(A[j].w > 0.5f);
      cnt += __popcll(b0) + __popcll(b1) + __popcll(b2) + __popcll(b3);
      if ((lane & 31) == 0) {
        uint4 v = (lane == 0)
          ? make_uint4((uint)b0, (uint)(b0 >> 32), (uint)b1, (uint)(b1 >> 32))
          : make_uint4((uint)b2, (uint)(b2 >> 32), (uint)b3, (uint)(b3 >> 32));
        *(uint4*)(dst + (bt * 4 + j) * 8 + (lane >> 5) * 4) = v;
      }
    }
#pragma unroll
    for (int j = 0; j < 4; ++j) { A[j] = B[j]; B[j] = C[j]; }
  }
  if (lane == 0) {
    float d = rsqrtf((float)(cnt + 1));
    dinv[row] = d;
    dk[kappa(row)] = d;
  }
  // prep, spread thin: blocks 0..255 -> 2 wT cols each; 256..287 -> lwb slice
  if (b < 256) {
#pragma unroll
    for (int kk = 0; kk < 2; ++kk) {
      int k = b * 2 + kk;
      wT[(size_t)t * 512 + k] = f2bf(w[(size_t)k * 256 + t]);
    }
  } else if (b < 288) {
    const int b2 = b - 256;
    const float4* s = (const float4*)lw + b2 * 512;
    uint2* d = (uint2*)lwb + b2 * 512;
#pragma unroll
    for (int ii = 0; ii < 2; ++ii) {
      float4 v = s[ii * 256 + t];
      uint2 p; p.x = pack2(v.x, v.y); p.y = pack2(v.z, v.w);
      d[ii * 256 + t] = p;
    }
  }
}

// ---------------- K2: PB + zRow = dk[k]*(x@w), bf16 MFMA ---------------------
__global__ __launch_bounds__(512) void k_xw(const float* __restrict__ x,
                                            const ushort* __restrict__ wT,
                                            const float* __restrict__ dk,
                                            ushort* __restrict__ PB,
                                            ushort* __restrict__ zRow) {
  __shared__ ushort xa[2][32 * 64];   // 8 KB dbuf
  __shared__ ushort zs[32 * 264];     // 16.9 KB, padded stride 264
  const int b = blockIdx.x;
  const int bp = (b & 3) * 64 + (b >> 2);
  const int t = threadIdx.x;
  const int lane = t & 63, wid = t >> 6;
  const int mg = wid >> 2, ng = wid & 3;
  const int rl = lane & 15, kg = lane >> 4;
  const int srow = t >> 4, sseg = t & 15;
  const int jrow = ((bp >> 3) << 8) + ((bp & 1) << 7) + ((bp >> 1) & 3) + srow * 4;
  const float4* xsrc = (const float4*)(x + (size_t)jrow * 512) + sseg;
  const int swb = (sseg * 8) ^ ((srow & 7) << 4);
  const int arow = mg * 16 + rl;
  float4 xv[8];
#pragma unroll
  for (int kc2 = 0; kc2 < 8; kc2++) xv[kc2] = xsrc[kc2 * 16];

  f32x4 acc[4];
#pragma unroll
  for (int q = 0; q < 4; q++) acc[q] = (f32x4){0.f, 0.f, 0.f, 0.f};

  {
    uint2 pk; pk.x = pack2(xv[0].x, xv[0].y); pk.y = pack2(xv[0].z, xv[0].w);
    *(uint2*)((char*)xa[0] + srow * 128 + swb) = pk;
  }
#pragma unroll
  for (int kc2 = 0; kc2 < 8; kc2++) {
    __syncthreads();
    if (kc2 < 7) {
      uint2 pk; pk.x = pack2(xv[kc2 + 1].x, xv[kc2 + 1].y);
      pk.y = pack2(xv[kc2 + 1].z, xv[kc2 + 1].w);
      *(uint2*)((char*)xa[(kc2 + 1) & 1] + srow * 128 + swb) = pk;
    }
#pragma unroll
    for (int ks = 0; ks < 2; ks++) {
      union { uint4 u; s16x8 s; } av;
      av.u = *(uint4*)((char*)xa[kc2 & 1] + arow * 128 + ((ks * 64 + kg * 16) ^ ((rl & 7) << 4)));
#pragma unroll
      for (int q = 0; q < 4; q++) {
        int n = ng * 64 + q * 16 + rl;
        union { uint4 u; s16x8 s; } bv;
        bv.u = *(const uint4*)(wT + (size_t)n * 512 + kc2 * 64 + ks * 32 + kg * 8);
        acc[q] = __builtin_amdgcn_mfma_f32_16x16x32_bf16(av.s, bv.s, acc[q], 0, 0, 0);
      }
    }
  }
  const int kb = bp * 32 + mg * 16 + kg * 4;
  float4 dk4 = *(const float4*)(dk + kb);
  const float dkv[4] = {dk4.x, dk4.y, dk4.z, dk4.w};
  char* pb0 = (char*)PB + (size_t)bp * 16384 + (mg * 2 + (kg >> 1)) * 256 + rl * 16 + (kg & 1) * 8;
  const int kk0 = mg * 16 + kg * 4;   // k offset within block's 32
#pragma unroll
  for (int q = 0; q < 4; q++) {
    int n = ng * 64 + q * 16 + rl;
    ushort zu[4];
#pragma unroll
    for (int r = 0; r < 4; r++) zu[r] = f2bf(acc[q][r] * dkv[r]);
    uint2 p;
    p.x = (uint)zu[0] | ((uint)zu[1] << 16);
    p.y = (uint)zu[2] | ((uint)zu[3] << 16);
    *(uint2*)(pb0 + (ng * 4 + q) * 1024) = p;
#pragma unroll
    for (int r = 0; r < 4; r++) zs[(kk0 + r) * 264 + n] = zu[r];
  }
  __syncthreads();
  {  // coalesced zRow out
    const int rr = t >> 4, seg = t & 15;
    uint4 v0 = *(uint4*)&zs[rr * 264 + seg * 16];
    uint4 v1 = *(uint4*)&zs[rr * 264 + seg * 16 + 8];
    ushort* dstz = zRow + (size_t)ikappa(bp * 32 + rr) * 256 + seg * 16;
    *(uint4*)dstz = v0;
    *(uint4*)(dstz + 8) = v1;
  }
}

// ---------------- K3: part2 = (binA[:,kc] @ z[kc])^T, bf16 -------------------
__global__ __launch_bounds__(512) void k_spmm(const uint* __restrict__ bits,
                                              const ushort* __restrict__ PB,
                                              ushort* __restrict__ part2) {
  __shared__ uint4 blds4[128 * 16];   // 32 KB: [row][granule g ^ (row&15)]
  __shared__ uint2 lut[16];
  const int bx = blockIdx.x;
  const int kc = bx & 3, mb = bx >> 2;
  const int m0 = mb * 128;
  const int t = threadIdx.x;
  const int lane = t & 63, wid = t >> 6;
  const int mg = wid >> 2, ng = wid & 3;
  const int rl = lane & 15, kg = lane >> 4;
  if (t < 16) {
    uint2 e;
    e.x = ((t & 1u) ? 0x3F80u : 0u) | ((t & 2u) ? 0x3F800000u : 0u);
    e.y = ((t & 4u) ? 0x3F80u : 0u) | ((t & 8u) ? 0x3F800000u : 0u);
    lut[t] = e;
  }
  {
    const int r = t >> 2, p = t & 3;
    const uint4* src = (const uint4*)(bits + (size_t)(m0 + r) * 256 + kc * 64);
#pragma unroll
    for (int i = 0; i < 4; ++i) {
      int g = p * 4 + i;
      blds4[r * 16 + (g ^ (r & 15))] = src[g];
    }
  }
  const char* zb0 = (const char*)PB + (size_t)kc * 64 * 16384 + ng * 4096 + kg * 256 + rl * 16;
  __syncthreads();

  uint4 bufA[4], bufB[4];
#pragma unroll
  for (int q = 0; q < 4; ++q) bufA[q] = *(const uint4*)(zb0 + q * 1024);

  f32x4 acc[4][4];
#pragma unroll
  for (int f = 0; f < 4; ++f)
#pragma unroll
    for (int q = 0; q < 4; ++q) acc[f][q] = (f32x4){0.f, 0.f, 0.f, 0.f};

  int abase[4];
#pragma unroll
  for (int f = 0; f < 4; ++f) abase[f] = (mg * 64 + f * 16 + rl) * 16;
  const int axor = rl;
  const uint shft = kg * 8;

  for (int a = 0; a < 16; ++a) {
    uint4 aw[4];
#pragma unroll
    for (int f = 0; f < 4; ++f) aw[f] = blds4[abase[f] + (a ^ axor)];
#pragma unroll
    for (int s = 0; s < 4; ++s) {
      const int ks = a * 4 + s;
      const uint4* use = (s & 1) ? bufB : bufA;
      uint4* nxt = (s & 1) ? bufA : bufB;
      if (ks < 63) {
#pragma unroll
        for (int q = 0; q < 4; ++q)
          nxt[q] = *(const uint4*)(zb0 + (size_t)(ks + 1) * 16384 + q * 1024);
      }
#pragma unroll
      for (int f = 0; f < 4; ++f) {
        uint wrd = (s == 0) ? aw[f].x : (s == 1) ? aw[f].y : (s == 2) ? aw[f].z : aw[f].w;
        uint byt = (wrd >> shft) & 0xFFu;
        uint2 lo = lut[byt & 0xFu];
        uint2 hi = lut[byt >> 4];
        union { uint4 u; s16x8 s8; } au;
        au.u = make_uint4(lo.x, lo.y, hi.x, hi.y);
#pragma unroll
        for (int q = 0; q < 4; ++q) {
          union { uint4 u; s16x8 s8; } bu; bu.u = use[q];
          acc[f][q] = __builtin_amdgcn_mfma_f32_16x16x32_bf16(au.s8, bu.s8, acc[f][q], 0, 0, 0);
        }
      }
    }
  }
#pragma unroll
  for (int f = 0; f < 4; ++f)
#pragma unroll
    for (int q = 0; q < 4; ++q) {
      int n = ng * 64 + q * 16 + rl;
      int mt = mb * 4 + mg * 2 + (f >> 1);
      int moff = (f & 1) * 16 + kg * 4;
      uint2 p;
      p.x = pack2(acc[f][q][0], acc[f][q][1]);
      p.y = pack2(acc[f][q][2], acc[f][q][3]);
      *(uint2*)(part2 + ((((size_t)mt * 4 + kc) * 256 + n) * 32 + moff)) = p;
    }
}

// ---------------- K4: h = relu(d_m*(sum part2 + zRow)); out = h @ lwb^T + lb -
__global__ __launch_bounds__(512) void k_lin(const ushort* __restrict__ part2,
                                             const ushort* __restrict__ zRow,
                                             const float* __restrict__ dinv,
                                             const ushort* __restrict__ lwb,
                                             const float* __restrict__ lb,
                                             float* __restrict__ out) {
  __shared__ ushort hA[32 * 256];
  __shared__ float sdinv[32];
  const int m0 = blockIdx.x * 32;
  const int t = threadIdx.x;
  if (t < 32) sdinv[t] = dinv[m0 + t];
  {
    const int n = t & 255, mh = t >> 8;
    float sum[16];
#pragma unroll
    for (int j = 0; j < 16; ++j)
      sum[j] = bf2f(zRow[(size_t)(m0 + mh * 16 + j) * 256 + n]);
#pragma unroll
    for (int kcp = 0; kcp < 4; kcp++) {
      const ushort* pp = part2 + (((size_t)blockIdx.x * 4 + kcp) * 256 + n) * 32 + mh * 16;
      uint4 pa = *(const uint4*)pp, pbq = *(const uint4*)(pp + 8);
      uint pu[8] = {pa.x, pa.y, pa.z, pa.w, pbq.x, pbq.y, pbq.z, pbq.w};
#pragma unroll
      for (int i = 0; i < 8; i++) {
        sum[2 * i]     += bf2f((ushort)(pu[i] & 0xFFFF));
        sum[2 * i + 1] += bf2f((ushort)(pu[i] >> 16));
      }
    }
    __syncthreads();   // sdinv visible
#pragma unroll
    for (int j = 0; j < 16; j++) {
      int m = mh * 16 + j;
      float h = sum[j] * sdinv[m];
      h = h > 0.f ? h : 0.f;
      *(ushort*)((char*)hA + m * 512 + ((n * 2) ^ ((m & 7) << 4))) = f2bf(h);
    }
  }
  __syncthreads();
  const int lane = t & 63, wid = t >> 6;
  const int rl = lane & 15, kg = lane >> 4;
  f32x4 acc[2][2];
#pragma unroll
  for (int f = 0; f < 2; f++)
#pragma unroll
    for (int q = 0; q < 2; q++) acc[f][q] = (f32x4){0.f, 0.f, 0.f, 0.f};

#pragma unroll
  for (int ks = 0; ks < 8; ks++) {
    union { uint4 u; s16x8 s; } av[2];
#pragma unroll
    for (int f = 0; f < 2; f++)
      av[f].u = *(uint4*)((char*)hA + (f * 16 + rl) * 512 + ((ks * 64 + kg * 16) ^ ((rl & 7) << 4)));
#pragma unroll
    for (int q = 0; q < 2; q++) {
      int no = wid * 32 + q * 16 + rl;
      union { uint4 u; s16x8 s; } bv;
      bv.u = *(const uint4*)(lwb + (size_t)no * 256 + ks * 32 + kg * 8);
#pragma unroll
      for (int f = 0; f < 2; f++)
        acc[f][q] = __builtin_amdgcn_mfma_f32_16x16x32_bf16(av[f].s, bv.s, acc[f][q], 0, 0, 0);
    }
  }
#pragma unroll
  for (int q = 0; q < 2; q++) {
    int no = wid * 32 + q * 16 + rl;
    float bb = lb[no];
#pragma unroll
    for (int f = 0; f < 2; f++) {
      int mbase = m0 + f * 16 + kg * 4;
#pragma unroll
      for (int r = 0; r < 4; r++)
        out[(size_t)(mbase + r) * 256 + no] = acc[f][q][r] + bb;
    }
  }
}

extern "C" void kernel_launch(void* const* d_in, const int* in_sizes, int n_in,
                              void* d_out, int out_size, void* d_ws, size_t ws_size,
                              hipStream_t stream) {
  const float* x   = (const float*)d_in[0];
  const float* adj = (const float*)d_in[1];
  const float* w   = (const float*)d_in[2];
  const float* lw  = (const float*)d_in[3];
  const float* lb  = (const float*)d_in[4];
  float* out = (float*)d_out;

  char* ws = (char*)d_ws;
  float*  dinv  = (float*)(ws + 0);                 // 32 KB
  float*  dk    = (float*)(ws + (32u << 10));       // 32 KB (permuted)
  ushort* lwb   = (ushort*)(ws + (128u << 10));     // 128 KB
  ushort* wT    = (ushort*)(ws + (256u << 10));     // 256 KB
  uint*   bits  = (uint*)(ws + (1ull << 20));       // 8 MB
  ushort* PB    = (ushort*)(ws + (9ull << 20));     // 4 MB (tiled z)
  ushort* part2 = (ushort*)(ws + (16ull << 20));    // 16 MB [mt][kc][n][m&31]
  ushort* zRow  = (ushort*)(ws + (48ull << 20));    // 4 MB  [m][n]

  hipLaunchKernelGGL(k_pack, dim3(2048), dim3(256), 0, stream, adj, w, lw, bits, dinv, dk, wT, lwb);
  hipLaunchKernelGGL(k_xw, dim3(256), dim3(512), 0, stream, x, wT, dk, PB, zRow);
  hipLaunchKernelGGL(k_spmm, dim3(256), dim3(512), 0, stream, bits, PB, part2);
  hipLaunchKernelGGL(k_lin, dim3(256), dim3(512), 0, stream, part2, zRow, dinv, lwb, lb, out);
}

// Round 14
// 118.606 us; speedup vs baseline: 1.6372x; 1.0151x over previous
//
#include <hip/hip_runtime.h>
#include <hip/hip_bf16.h>

typedef __attribute__((ext_vector_type(4))) float f32x4;
typedef __attribute__((ext_vector_type(8))) short s16x8;
typedef unsigned int uint;
typedef unsigned short ushort;
typedef unsigned long long u64;

// N=8192, INP=512, OUT=256
// out = relu(D^-1/2 (binA+I) D^-1/2 (x@w)) @ lin_w^T + lin_b
// binA packed via wave ballot (k permuted by kappa); bf16 MFMA GEMMs.
// PB tiled: byte((n,k)) = (k>>5)*16384+(n>>4)*1024+((k>>3)&3)*256+(n&15)*16+(k&7)*2
// part2[mt 256][kc 4][n 256][m&31 32] bf16
// R14: k_pack un-capped VGPRs (was 64-reg bound -> likely scratch spills with
//      12-float4 pipeline) + nontemporal adj loads (preserve L3 for bits/x/wT).

__device__ inline ushort f2bf(float f) {
  union { float f; uint u; } v; v.f = f;
  uint r = (v.u + 0x7FFFu + ((v.u >> 16) & 1u)) >> 16;   // RNE
  return (ushort)r;
}
__device__ inline float bf2f(ushort h) { union { uint u; float f; } v; v.u = ((uint)h) << 16; return v.f; }
__device__ inline uint pack2(float a, float b) { return (uint)f2bf(a) | ((uint)f2bf(b) << 16); }
__device__ inline int kappa(int j) {
  return (j & ~255) | ((j & 3) << 6) | (((j >> 7) & 1) << 5) | ((j >> 2) & 31);
}
__device__ inline int ikappa(int k) {
  return (k & ~255) | ((k >> 6) & 3) | (((k >> 5) & 1) << 7) | ((k & 31) << 2);
}

// ---------------- K1: ballot bit-pack, 1 row/wave, depth-2 pipeline ----------
// No launch_bounds min: let compiler allocate regs for the 12-f32x4 pipeline
// without spilling (16 waves/CU suffices: BW-latency product ~22 KB/CU).
__global__ __launch_bounds__(256) void k_pack(const float* __restrict__ adj,
                                              const float* __restrict__ w,
                                              const float* __restrict__ lw,
                                              uint* __restrict__ bits,
                                              float* __restrict__ dinv,
                                              float* __restrict__ dk,
                                              ushort* __restrict__ wT,
                                              ushort* __restrict__ lwb) {
  const int t = threadIdx.x, lane = t & 63, wv = t >> 6;
  const int b = blockIdx.x;
  const int row = b * 4 + wv;
  const f32x4* src = (const f32x4*)(adj + (size_t)row * 8192) + lane;
  uint* dst = bits + (size_t)row * 256;
  f32x4 A[4], B[4], C[4];
#pragma unroll
  for (int j = 0; j < 4; ++j) A[j] = __builtin_nontemporal_load(src + j * 64);
#pragma unroll
  for (int j = 0; j < 4; ++j) B[j] = __builtin_nontemporal_load(src + 256 + j * 64);
  int cnt = 0;
#pragma unroll
  for (int bt = 0; bt < 8; ++bt) {
    if (bt + 2 < 8) {
#pragma unroll
      for (int j = 0; j < 4; ++j)
        C[j] = __builtin_nontemporal_load(src + (bt + 2) * 256 + j * 64);
    }
#pragma unroll
    for (int j = 0; j < 4; ++j) {
      u64 b0 = __ballot(A[j].x > 0.5f), b1 = __ballot(A[j].y > 0.5f);
      u64 b2 = __ballot(A[j].z > 0.5f), b3 = __ballot(A[j].w > 0.5f);
      cnt += __popcll(b0) + __popcll(b1) + __popcll(b2) + __popcll(b3);
      if ((lane & 31) == 0) {
        uint4 v = (lane == 0)
          ? make_uint4((uint)b0, (uint)(b0 >> 32), (uint)b1, (uint)(b1 >> 32))
          : make_uint4((uint)b2, (uint)(b2 >> 32), (uint)b3, (uint)(b3 >> 32));
        *(uint4*)(dst + (bt * 4 + j) * 8 + (lane >> 5) * 4) = v;
      }
    }
#pragma unroll
    for (int j = 0; j < 4; ++j) { A[j] = B[j]; B[j] = C[j]; }
  }
  if (lane == 0) {
    float d = rsqrtf((float)(cnt + 1));
    dinv[row] = d;
    dk[kappa(row)] = d;
  }
  // prep, spread thin: blocks 0..255 -> 2 wT cols each; 256..287 -> lwb slice
  if (b < 256) {
#pragma unroll
    for (int kk = 0; kk < 2; ++kk) {
      int k = b * 2 + kk;
      wT[(size_t)t * 512 + k] = f2bf(w[(size_t)k * 256 + t]);
    }
  } else if (b < 288) {
    const int b2 = b - 256;
    const float4* s = (const float4*)lw + b2 * 512;
    uint2* d = (uint2*)lwb + b2 * 512;
#pragma unroll
    for (int ii = 0; ii < 2; ++ii) {
      float4 v = s[ii * 256 + t];
      uint2 p; p.x = pack2(v.x, v.y); p.y = pack2(v.z, v.w);
      d[ii * 256 + t] = p;
    }
  }
}

// ---------------- K2: PB + zRow = dk[k]*(x@w), bf16 MFMA ---------------------
__global__ __launch_bounds__(512) void k_xw(const float* __restrict__ x,
                                            const ushort* __restrict__ wT,
                                            const float* __restrict__ dk,
                                            ushort* __restrict__ PB,
                                            ushort* __restrict__ zRow) {
  __shared__ ushort xa[2][32 * 64];   // 8 KB dbuf
  __shared__ ushort zs[32 * 264];     // 16.9 KB, padded stride 264
  const int b = blockIdx.x;
  const int bp = (b & 3) * 64 + (b >> 2);
  const int t = threadIdx.x;
  const int lane = t & 63, wid = t >> 6;
  const int mg = wid >> 2, ng = wid & 3;
  const int rl = lane & 15, kg = lane >> 4;
  const int srow = t >> 4, sseg = t & 15;
  const int jrow = ((bp >> 3) << 8) + ((bp & 1) << 7) + ((bp >> 1) & 3) + srow * 4;
  const float4* xsrc = (const float4*)(x + (size_t)jrow * 512) + sseg;
  const int swb = (sseg * 8) ^ ((srow & 7) << 4);
  const int arow = mg * 16 + rl;
  float4 xv[8];
#pragma unroll
  for (int kc2 = 0; kc2 < 8; kc2++) xv[kc2] = xsrc[kc2 * 16];

  f32x4 acc[4];
#pragma unroll
  for (int q = 0; q < 4; q++) acc[q] = (f32x4){0.f, 0.f, 0.f, 0.f};

  {
    uint2 pk; pk.x = pack2(xv[0].x, xv[0].y); pk.y = pack2(xv[0].z, xv[0].w);
    *(uint2*)((char*)xa[0] + srow * 128 + swb) = pk;
  }
#pragma unroll
  for (int kc2 = 0; kc2 < 8; kc2++) {
    __syncthreads();
    if (kc2 < 7) {
      uint2 pk; pk.x = pack2(xv[kc2 + 1].x, xv[kc2 + 1].y);
      pk.y = pack2(xv[kc2 + 1].z, xv[kc2 + 1].w);
      *(uint2*)((char*)xa[(kc2 + 1) & 1] + srow * 128 + swb) = pk;
    }
#pragma unroll
    for (int ks = 0; ks < 2; ks++) {
      union { uint4 u; s16x8 s; } av;
      av.u = *(uint4*)((char*)xa[kc2 & 1] + arow * 128 + ((ks * 64 + kg * 16) ^ ((rl & 7) << 4)));
#pragma unroll
      for (int q = 0; q < 4; q++) {
        int n = ng * 64 + q * 16 + rl;
        union { uint4 u; s16x8 s; } bv;
        bv.u = *(const uint4*)(wT + (size_t)n * 512 + kc2 * 64 + ks * 32 + kg * 8);
        acc[q] = __builtin_amdgcn_mfma_f32_16x16x32_bf16(av.s, bv.s, acc[q], 0, 0, 0);
      }
    }
  }
  const int kb = bp * 32 + mg * 16 + kg * 4;
  float4 dk4 = *(const float4*)(dk + kb);
  const float dkv[4] = {dk4.x, dk4.y, dk4.z, dk4.w};
  char* pb0 = (char*)PB + (size_t)bp * 16384 + (mg * 2 + (kg >> 1)) * 256 + rl * 16 + (kg & 1) * 8;
  const int kk0 = mg * 16 + kg * 4;   // k offset within block's 32
#pragma unroll
  for (int q = 0; q < 4; q++) {
    int n = ng * 64 + q * 16 + rl;
    ushort zu[4];
#pragma unroll
    for (int r = 0; r < 4; r++) zu[r] = f2bf(acc[q][r] * dkv[r]);
    uint2 p;
    p.x = (uint)zu[0] | ((uint)zu[1] << 16);
    p.y = (uint)zu[2] | ((uint)zu[3] << 16);
    *(uint2*)(pb0 + (ng * 4 + q) * 1024) = p;
#pragma unroll
    for (int r = 0; r < 4; r++) zs[(kk0 + r) * 264 + n] = zu[r];
  }
  __syncthreads();
  {  // coalesced zRow out
    const int rr = t >> 4, seg = t & 15;
    uint4 v0 = *(uint4*)&zs[rr * 264 + seg * 16];
    uint4 v1 = *(uint4*)&zs[rr * 264 + seg * 16 + 8];
    ushort* dstz = zRow + (size_t)ikappa(bp * 32 + rr) * 256 + seg * 16;
    *(uint4*)dstz = v0;
    *(uint4*)(dstz + 8) = v1;
  }
}

// ---------------- K3: part2 = (binA[:,kc] @ z[kc])^T, bf16 -------------------
__global__ __launch_bounds__(512) void k_spmm(const uint* __restrict__ bits,
                                              const ushort* __restrict__ PB,
                                              ushort* __restrict__ part2) {
  __shared__ uint4 blds4[128 * 16];   // 32 KB: [row][granule g ^ (row&15)]
  __shared__ uint2 lut[16];
  const int bx = blockIdx.x;
  const int kc = bx & 3, mb = bx >> 2;
  const int m0 = mb * 128;
  const int t = threadIdx.x;
  const int lane = t & 63, wid = t >> 6;
  const int mg = wid >> 2, ng = wid & 3;
  const int rl = lane & 15, kg = lane >> 4;
  if (t < 16) {
    uint2 e;
    e.x = ((t & 1u) ? 0x3F80u : 0u) | ((t & 2u) ? 0x3F800000u : 0u);
    e.y = ((t & 4u) ? 0x3F80u : 0u) | ((t & 8u) ? 0x3F800000u : 0u);
    lut[t] = e;
  }
  {
    const int r = t >> 2, p = t & 3;
    const uint4* src = (const uint4*)(bits + (size_t)(m0 + r) * 256 + kc * 64);
#pragma unroll
    for (int i = 0; i < 4; ++i) {
      int g = p * 4 + i;
      blds4[r * 16 + (g ^ (r & 15))] = src[g];
    }
  }
  const char* zb0 = (const char*)PB + (size_t)kc * 64 * 16384 + ng * 4096 + kg * 256 + rl * 16;
  __syncthreads();

  uint4 bufA[4], bufB[4];
#pragma unroll
  for (int q = 0; q < 4; ++q) bufA[q] = *(const uint4*)(zb0 + q * 1024);

  f32x4 acc[4][4];
#pragma unroll
  for (int f = 0; f < 4; ++f)
#pragma unroll
    for (int q = 0; q < 4; ++q) acc[f][q] = (f32x4){0.f, 0.f, 0.f, 0.f};

  int abase[4];
#pragma unroll
  for (int f = 0; f < 4; ++f) abase[f] = (mg * 64 + f * 16 + rl) * 16;
  const int axor = rl;
  const uint shft = kg * 8;

  for (int a = 0; a < 16; ++a) {
    uint4 aw[4];
#pragma unroll
    for (int f = 0; f < 4; ++f) aw[f] = blds4[abase[f] + (a ^ axor)];
#pragma unroll
    for (int s = 0; s < 4; ++s) {
      const int ks = a * 4 + s;
      const uint4* use = (s & 1) ? bufB : bufA;
      uint4* nxt = (s & 1) ? bufA : bufB;
      if (ks < 63) {
#pragma unroll
        for (int q = 0; q < 4; ++q)
          nxt[q] = *(const uint4*)(zb0 + (size_t)(ks + 1) * 16384 + q * 1024);
      }
#pragma unroll
      for (int f = 0; f < 4; ++f) {
        uint wrd = (s == 0) ? aw[f].x : (s == 1) ? aw[f].y : (s == 2) ? aw[f].z : aw[f].w;
        uint byt = (wrd >> shft) & 0xFFu;
        uint2 lo = lut[byt & 0xFu];
        uint2 hi = lut[byt >> 4];
        union { uint4 u; s16x8 s8; } au;
        au.u = make_uint4(lo.x, lo.y, hi.x, hi.y);
#pragma unroll
        for (int q = 0; q < 4; ++q) {
          union { uint4 u; s16x8 s8; } bu; bu.u = use[q];
          acc[f][q] = __builtin_amdgcn_mfma_f32_16x16x32_bf16(au.s8, bu.s8, acc[f][q], 0, 0, 0);
        }
      }
    }
  }
#pragma unroll
  for (int f = 0; f < 4; ++f)
#pragma unroll
    for (int q = 0; q < 4; ++q) {
      int n = ng * 64 + q * 16 + rl;
      int mt = mb * 4 + mg * 2 + (f >> 1);
      int moff = (f & 1) * 16 + kg * 4;
      uint2 p;
      p.x = pack2(acc[f][q][0], acc[f][q][1]);
      p.y = pack2(acc[f][q][2], acc[f][q][3]);
      *(uint2*)(part2 + ((((size_t)mt * 4 + kc) * 256 + n) * 32 + moff)) = p;
    }
}

// ---------------- K4: h = relu(d_m*(sum part2 + zRow)); out = h @ lwb^T + lb -
__global__ __launch_bounds__(512) void k_lin(const ushort* __restrict__ part2,
                                             const ushort* __restrict__ zRow,
                                             const float* __restrict__ dinv,
                                             const ushort* __restrict__ lwb,
                                             const float* __restrict__ lb,
                                             float* __restrict__ out) {
  __shared__ ushort hA[32 * 256];
  __shared__ float sdinv[32];
  const int m0 = blockIdx.x * 32;
  const int t = threadIdx.x;
  if (t < 32) sdinv[t] = dinv[m0 + t];
  {
    const int n = t & 255, mh = t >> 8;
    float sum[16];
#pragma unroll
    for (int j = 0; j < 16; ++j)
      sum[j] = bf2f(zRow[(size_t)(m0 + mh * 16 + j) * 256 + n]);
#pragma unroll
    for (int kcp = 0; kcp < 4; kcp++) {
      const ushort* pp = part2 + (((size_t)blockIdx.x * 4 + kcp) * 256 + n) * 32 + mh * 16;
      uint4 pa = *(const uint4*)pp, pbq = *(const uint4*)(pp + 8);
      uint pu[8] = {pa.x, pa.y, pa.z, pa.w, pbq.x, pbq.y, pbq.z, pbq.w};
#pragma unroll
      for (int i = 0; i < 8; i++) {
        sum[2 * i]     += bf2f((ushort)(pu[i] & 0xFFFF));
        sum[2 * i + 1] += bf2f((ushort)(pu[i] >> 16));
      }
    }
    __syncthreads();   // sdinv visible
#pragma unroll
    for (int j = 0; j < 16; j++) {
      int m = mh * 16 + j;
      float h = sum[j] * sdinv[m];
      h = h > 0.f ? h : 0.f;
      *(ushort*)((char*)hA + m * 512 + ((n * 2) ^ ((m & 7) << 4))) = f2bf(h);
    }
  }
  __syncthreads();
  const int lane = t & 63, wid = t >> 6;
  const int rl = lane & 15, kg = lane >> 4;
  f32x4 acc[2][2];
#pragma unroll
  for (int f = 0; f < 2; f++)
#pragma unroll
    for (int q = 0; q < 2; q++) acc[f][q] = (f32x4){0.f, 0.f, 0.f, 0.f};

#pragma unroll
  for (int ks = 0; ks < 8; ks++) {
    union { uint4 u; s16x8 s; } av[2];
#pragma unroll
    for (int f = 0; f < 2; f++)
      av[f].u = *(uint4*)((char*)hA + (f * 16 + rl) * 512 + ((ks * 64 + kg * 16) ^ ((rl & 7) << 4)));
#pragma unroll
    for (int q = 0; q < 2; q++) {
      int no = wid * 32 + q * 16 + rl;
      union { uint4 u; s16x8 s; } bv;
      bv.u = *(const uint4*)(lwb + (size_t)no * 256 + ks * 32 + kg * 8);
#pragma unroll
      for (int f = 0; f < 2; f++)
        acc[f][q] = __builtin_amdgcn_mfma_f32_16x16x32_bf16(av[f].s, bv.s, acc[f][q], 0, 0, 0);
    }
  }
#pragma unroll
  for (int q = 0; q < 2; q++) {
    int no = wid * 32 + q * 16 + rl;
    float bb = lb[no];
#pragma unroll
    for (int f = 0; f < 2; f++) {
      int mbase = m0 + f * 16 + kg * 4;
#pragma unroll
      for (int r = 0; r < 4; r++)
        out[(size_t)(mbase + r) * 256 + no] = acc[f][q][r] + bb;
    }
  }
}

extern "C" void kernel_launch(void* const* d_in, const int* in_sizes, int n_in,
                              void* d_out, int out_size, void* d_ws, size_t ws_size,
                              hipStream_t stream) {
  const float* x   = (const float*)d_in[0];
  const float* adj = (const float*)d_in[1];
  const float* w   = (const float*)d_in[2];
  const float* lw  = (const float*)d_in[3];
  const float* lb  = (const float*)d_in[4];
  float* out = (float*)d_out;

  char* ws = (char*)d_ws;
  float*  dinv  = (float*)(ws + 0);                 // 32 KB
  float*  dk    = (float*)(ws + (32u << 10));       // 32 KB (permuted)
  ushort* lwb   = (ushort*)(ws + (128u << 10));     // 128 KB
  ushort* wT    = (ushort*)(ws + (256u << 10));     // 256 KB
  uint*   bits  = (uint*)(ws + (1ull << 20));       // 8 MB
  ushort* PB    = (ushort*)(ws + (9ull << 20));     // 4 MB (tiled z)
  ushort* part2 = (ushort*)(ws + (16ull << 20));    // 16 MB [mt][kc][n][m&31]
  ushort* zRow  = (ushort*)(ws + (48ull << 20));    // 4 MB  [m][n]

  hipLaunchKernelGGL(k_pack, dim3(2048), dim3(256), 0, stream, adj, w, lw, bits, dinv, dk, wT, lwb);
  hipLaunchKernelGGL(k_xw, dim3(256), dim3(512), 0, stream, x, wT, dk, PB, zRow);
  hipLaunchKernelGGL(k_spmm, dim3(256), dim3(512), 0, stream, bits, PB, part2);
  hipLaunchKernelGGL(k_lin, dim3(256), dim3(512), 0, stream, part2, zRow, dinv, lwb, lb, out);
}